// Round 12
// baseline (332.988 us; speedup 1.0000x reference)
//
#include <hip/hip_runtime.h>
#include <hip/hip_bf16.h>
#include <cstdint>

#define DIN 1024
#define DH  2048
#define DR  256
#define SEQ 4096
#define NB  4
#define MTOK (NB*SEQ)   // 16384
#define NCHUNK 64
#define CL (SEQ/NCHUNK) // 64
#define NCH (NB*DH)     // 8192 (b,ch) lanes

typedef __attribute__((ext_vector_type(8))) short bf16x8;
typedef __attribute__((ext_vector_type(4))) float f32x4;

__device__ __forceinline__ unsigned short f2bf(float f) {
  union { float f; unsigned u; } v; v.f = f;
  unsigned r = v.u + 0x7fffu + ((v.u >> 16) & 1u);
  return (unsigned short)(r >> 16);
}

__device__ __forceinline__ float bf2f(unsigned s) {
  union { unsigned u; float f; } v; v.u = s << 16; return v.f;
}

// pack two f32 -> (bf16(a) | bf16(b)<<16) via HW round-to-nearest-even
__device__ __forceinline__ unsigned pack_ab(float a, float b) {
  unsigned r;
  asm("v_cvt_pk_bf16_f32 %0, %1, %2" : "=v"(r) : "v"(a), "v"(b));
  return r;
}

__device__ __forceinline__ unsigned pack2bf(float a, float b) {
  unsigned r;
  asm("v_cvt_pk_bf16_f32 %0, %1, %2" : "=v"(r) : "v"(a), "v"(b));
  return r;
}

__device__ __forceinline__ float fast_rcp(float x) {
  float r;
  asm("v_rcp_f32_e32 %0, %1" : "=v"(r) : "v"(x));
  return r;
}

__device__ __forceinline__ float sigmoidf_(float x) {
  return fast_rcp(1.0f + __expf(-x));
}

// ---- single merged cast kernel: all 5 f32->bf16 casts, region-resolved ----
__global__ void cast_all(const float* __restrict__ x,  const float* __restrict__ Wv,
                         const float* __restrict__ Wg, const float* __restrict__ Wd,
                         const float* __restrict__ We,
                         unsigned short* __restrict__ Xb,  unsigned short* __restrict__ Wvb,
                         unsigned short* __restrict__ Wgb, unsigned short* __restrict__ Wdb,
                         unsigned short* __restrict__ Web) {
  const int total = 5439488;
  for (int i = blockIdx.x * blockDim.x + threadIdx.x; i < total;
       i += gridDim.x * blockDim.x) {
    const float* src; unsigned short* dst;
    int li, r, c4, ld, cols;
    if (i < 4194304)      { li = i;           src = x;  dst = Xb;  r = li >> 8; c4 = li & 255; ld = 1024; cols = 1024; }
    else if (i < 4718592) { li = i - 4194304; src = Wv; dst = Wvb; r = li >> 8; c4 = li & 255; ld = 1024; cols = 1024; }
    else if (i < 5242880) { li = i - 4718592; src = Wg; dst = Wgb; r = li >> 8; c4 = li & 255; ld = 3072; cols = 1024; }
    else if (i < 5308416) { li = i - 5242880; src = Wd; dst = Wdb; r = li >> 8; c4 = li & 255; ld = 3072; cols = 1024; }
    else                  { li = i - 5308416; src = We; dst = Web; r = li >> 6; c4 = li & 63;  ld = 256;  cols = 256; }
    const float4 v = *reinterpret_cast<const float4*>(src + (size_t)r * ld + c4 * 4);
    uint2 o;
    o.x = pack2bf(v.x, v.y);
    o.y = pack2bf(v.z, v.w);
    *reinterpret_cast<uint2*>(dst + (size_t)r * cols + c4 * 4) = o;
  }
}

// ---- hidden-part projections ----
__global__ void hd_kernel(const float* __restrict__ Wg, const float* __restrict__ Wd,
                          const float* __restrict__ hidden,
                          float* __restrict__ hd_gate, float* __restrict__ hd_delta) {
  int wid  = (blockIdx.x * blockDim.x + threadIdx.x) >> 6;
  int lane = threadIdx.x & 63;
  if (wid >= DH + DR) return;
  const float* wrow;
  int ch; bool isGate;
  if (wid < DH) { isGate = true;  ch = wid;      wrow = Wg + (size_t)ch * (DIN + DH) + DIN; }
  else          { isGate = false; ch = wid - DH; wrow = Wd + (size_t)ch * (DIN + DH) + DIN; }
  float acc[NB] = {0.f, 0.f, 0.f, 0.f};
  for (int k = lane; k < DH; k += 64) {
    float w = wrow[k];
    #pragma unroll
    for (int b = 0; b < NB; b++) acc[b] += w * hidden[b * DH + k];
  }
  #pragma unroll
  for (int b = 0; b < NB; b++) {
    float v = acc[b];
    #pragma unroll
    for (int off = 32; off; off >>= 1) v += __shfl_down(v, off);
    if (lane == 0) {
      if (isGate) hd_gate[b * DH + ch] = v;
      else        hd_delta[b * DR + ch] = v;
    }
  }
}

// ---- async LDS staging via global_load_lds (linear LDS dest, pre-swizzled
//      SOURCE, swizzled read). Tile = [rows][64] bf16. ----
__device__ __forceinline__ void stage_async(const unsigned short* __restrict__ src,
                                            int src_ld, unsigned short* lds,
                                            int rows, int wid, int lane) {
  int r8 = lane >> 3;
  int c  = (lane & 7) ^ (r8 & 7);
  const unsigned short* g0 = src + (size_t)r8 * src_ld + c * 8;
  int nsegs = rows >> 3;
  for (int s = wid; s < nsegs; s += 4) {
    const unsigned short* g = g0 + (size_t)(s * 8) * src_ld;
    __builtin_amdgcn_global_load_lds(
        (const __attribute__((address_space(1))) void*)g,
        (__attribute__((address_space(3))) void*)(lds + s * 512),
        16, 0, 0);
  }
}

__device__ __forceinline__ bf16x8 read_frag(const unsigned short* lds, int row,
                                            int kk, int lane) {
  int c = (kk * 4 + (lane >> 4)) ^ (row & 7);
  return *reinterpret_cast<const bf16x8*>(lds + row * 64 + c * 8);
}

// ---- GEMM: P = silu(Xb @ Wd_x^T + hd_delta)  -> bf16 [MTOK][DR]
__global__ __launch_bounds__(256, 4) void gemm_P(
    const unsigned short* __restrict__ Xb, const unsigned short* __restrict__ Wdb,
    const float* __restrict__ hd_delta, unsigned short* __restrict__ P) {
  __shared__ __align__(16) unsigned short As[128 * 64];
  __shared__ __align__(16) unsigned short Bs[64 * 64];
  int tid = threadIdx.x, lane = tid & 63, wid = tid >> 6;
  int wm = wid >> 1, wn = wid & 1;
  int bm0 = blockIdx.x * 128;
  int bn0 = blockIdx.y * 64;
  f32x4 acc[4][2];
  #pragma unroll
  for (int m = 0; m < 4; m++)
    #pragma unroll
    for (int n = 0; n < 2; n++) acc[m][n] = (f32x4){0.f, 0.f, 0.f, 0.f};

  for (int k0 = 0; k0 < DIN; k0 += 64) {
    stage_async(Xb + (size_t)bm0 * DIN + k0, DIN, As, 128, wid, lane);
    stage_async(Wdb + (size_t)bn0 * DIN + k0, DIN, Bs, 64, wid, lane);
    __syncthreads();
    #pragma unroll
    for (int kk = 0; kk < 2; kk++) {
      bf16x8 af[4], bf[2];
      #pragma unroll
      for (int m = 0; m < 4; m++) af[m] = read_frag(As, wm * 64 + m * 16 + (lane & 15), kk, lane);
      #pragma unroll
      for (int n = 0; n < 2; n++) bf[n] = read_frag(Bs, wn * 32 + n * 16 + (lane & 15), kk, lane);
      #pragma unroll
      for (int m = 0; m < 4; m++)
        #pragma unroll
        for (int n = 0; n < 2; n++)
          acc[m][n] = __builtin_amdgcn_mfma_f32_16x16x32_bf16(af[m], bf[n], acc[m][n], 0, 0, 0);
    }
    __syncthreads();
  }
  int batch = bm0 >> 12;
  #pragma unroll
  for (int n = 0; n < 2; n++) {
    int ch = bn0 + wn * 32 + n * 16 + (lane & 15);
    float hd = hd_delta[batch * DR + ch];
    #pragma unroll
    for (int m = 0; m < 4; m++) {
      #pragma unroll
      for (int r = 0; r < 4; r++) {
        int tok = bm0 + wm * 64 + m * 16 + (lane >> 4) * 4 + r;
        float v = acc[m][n][r] + hd;
        v = v * sigmoidf_(v);   // silu
        P[(size_t)tok * DR + ch] = f2bf(v);
      }
    }
  }
}

// ---- fused GEMM producing packed (a,b) bf16 pairs + per-chunk scan partials ----
__global__ __launch_bounds__(256, 4) void gemm_fused(
    const unsigned short* __restrict__ Xb, const unsigned short* __restrict__ Wvb,
    const unsigned short* __restrict__ Wgb, const unsigned short* __restrict__ P,
    const unsigned short* __restrict__ Web,
    const float* __restrict__ b_value, const float* __restrict__ b_gate,
    const float* __restrict__ b_expand, const float* __restrict__ hd_gate,
    unsigned* __restrict__ ws_ab, float2* __restrict__ partial) {
  __shared__ __align__(16) unsigned short As[128 * 64];
  __shared__ __align__(16) unsigned short Bv[64 * 64];
  __shared__ __align__(16) unsigned short Bg[64 * 64];
  int tid = threadIdx.x, lane = tid & 63, wid = tid >> 6;
  int wm = wid >> 1, wn = wid & 1;
  int bm0 = blockIdx.x * 128;
  int bn0 = blockIdx.y * 64;
  f32x4 acc_v[4][2], acc_g[4][2], acc_d[4][2];
  #pragma unroll
  for (int m = 0; m < 4; m++)
    #pragma unroll
    for (int n = 0; n < 2; n++) {
      acc_v[m][n] = (f32x4){0.f, 0.f, 0.f, 0.f};
      acc_g[m][n] = (f32x4){0.f, 0.f, 0.f, 0.f};
      acc_d[m][n] = (f32x4){0.f, 0.f, 0.f, 0.f};
    }

  // K1: value + gate projections (share the X tile)
  for (int k0 = 0; k0 < DIN; k0 += 64) {
    stage_async(Xb + (size_t)bm0 * DIN + k0, DIN, As, 128, wid, lane);
    stage_async(Wvb + (size_t)bn0 * DIN + k0, DIN, Bv, 64, wid, lane);
    stage_async(Wgb + (size_t)bn0 * DIN + k0, DIN, Bg, 64, wid, lane);
    __syncthreads();
    #pragma unroll
    for (int kk = 0; kk < 2; kk++) {
      bf16x8 af[4], bvf[2], bgf[2];
      #pragma unroll
      for (int m = 0; m < 4; m++) af[m] = read_frag(As, wm * 64 + m * 16 + (lane & 15), kk, lane);
      #pragma unroll
      for (int n = 0; n < 2; n++) {
        bvf[n] = read_frag(Bv, wn * 32 + n * 16 + (lane & 15), kk, lane);
        bgf[n] = read_frag(Bg, wn * 32 + n * 16 + (lane & 15), kk, lane);
      }
      #pragma unroll
      for (int m = 0; m < 4; m++)
        #pragma unroll
        for (int n = 0; n < 2; n++) {
          acc_v[m][n] = __builtin_amdgcn_mfma_f32_16x16x32_bf16(af[m], bvf[n], acc_v[m][n], 0, 0, 0);
          acc_g[m][n] = __builtin_amdgcn_mfma_f32_16x16x32_bf16(af[m], bgf[n], acc_g[m][n], 0, 0, 0);
        }
    }
    __syncthreads();
  }
  // K2: delta expand (P @ We^T), K = 256
  for (int k0 = 0; k0 < DR; k0 += 64) {
    stage_async(P + (size_t)bm0 * DR + k0, DR, As, 128, wid, lane);
    stage_async(Web + (size_t)bn0 * DR + k0, DR, Bv, 64, wid, lane);
    __syncthreads();
    #pragma unroll
    for (int kk = 0; kk < 2; kk++) {
      bf16x8 af[4], bef[2];
      #pragma unroll
      for (int m = 0; m < 4; m++) af[m] = read_frag(As, wm * 64 + m * 16 + (lane & 15), kk, lane);
      #pragma unroll
      for (int n = 0; n < 2; n++) bef[n] = read_frag(Bv, wn * 32 + n * 16 + (lane & 15), kk, lane);
      #pragma unroll
      for (int m = 0; m < 4; m++)
        #pragma unroll
        for (int n = 0; n < 2; n++)
          acc_d[m][n] = __builtin_amdgcn_mfma_f32_16x16x32_bf16(af[m], bef[n], acc_d[m][n], 0, 0, 0);
    }
    __syncthreads();
  }
  // epilogue: pack a = 1-gate, b = gate*(silu(v)+delta); also compose the
  // wave's 64-token chunk aggregate (A,B) per channel from the ROUNDED values
  int batch = bm0 >> 12;
  int cbase = ((bm0 & (SEQ - 1)) >> 6) + wm;   // chunk index within batch
  int q = lane >> 4;
  #pragma unroll
  for (int n = 0; n < 2; n++) {
    int ch = bn0 + wn * 32 + n * 16 + (lane & 15);
    float bv_ = b_value[ch];
    float bg_ = b_gate[ch] + hd_gate[batch * DH + ch];
    float be_ = b_expand[ch];
    unsigned pk[4][4];
    #pragma unroll
    for (int m = 0; m < 4; m++) {
      #pragma unroll
      for (int r = 0; r < 4; r++) {
        int tok = bm0 + wm * 64 + m * 16 + q * 4 + r;
        float vv = acc_v[m][n][r] + bv_;
        vv = vv * sigmoidf_(vv);                       // silu(value)
        float gg = sigmoidf_(acc_g[m][n][r] + bg_);    // gate
        float dd = acc_d[m][n][r] + be_;               // delta
        unsigned pw = pack_ab(1.0f - gg, gg * (vv + dd));
        pk[m][r] = pw;
        ws_ab[(size_t)tok * DH + ch] = pw;
      }
    }
    // chunk composition: per-lane 4-run, ordered butterfly over q, fold over m
    float A = 1.f, B = 0.f;
    #pragma unroll
    for (int m = 0; m < 4; m++) {
      float Am = 1.f, Bm = 0.f;
      #pragma unroll
      for (int r = 0; r < 4; r++) {
        float ar = bf2f(pk[m][r] & 0xffffu), br = bf2f(pk[m][r] >> 16);
        Bm = fmaf(ar, Bm, br); Am *= ar;
      }
      // ordered butterfly across q (lane bits 4,5): compose lower-q first
      {
        float Ao = __shfl_xor(Am, 16), Bo = __shfl_xor(Bm, 16);
        bool hi = (lane >> 4) & 1;
        float A1 = hi ? Ao : Am, B1 = hi ? Bo : Bm;
        float A2 = hi ? Am : Ao, B2 = hi ? Bm : Bo;
        Am = A2 * A1; Bm = fmaf(A2, B1, B2);
      }
      {
        float Ao = __shfl_xor(Am, 32), Bo = __shfl_xor(Bm, 32);
        bool hi = (lane >> 5) & 1;
        float A1 = hi ? Ao : Am, B1 = hi ? Bo : Bm;
        float A2 = hi ? Am : Ao, B2 = hi ? Bm : Bo;
        Am = A2 * A1; Bm = fmaf(A2, B1, B2);
      }
      B = fmaf(Am, B, Bm); A *= Am;
    }
    if (lane < 16) {
      float2 w = {A, B};
      partial[(size_t)cbase * NCH + batch * DH + ch] = w;
    }
  }
}

// ---- scan pass B: sequential scan over chunk aggregates, emit prefixes + h_last ----
__global__ void scan_chunks(const float2* __restrict__ partial,
                            const float* __restrict__ hidden,
                            float* __restrict__ prefix, float* __restrict__ out) {
  int g = blockIdx.x * 256 + threadIdx.x;    // 8192
  float H = hidden[g];
  for (int c = 0; c < NCHUNK; c++) {
    prefix[c * NCH + g] = H;
    float2 AB = partial[(size_t)c * NCH + g];
    H = fmaf(AB.x, H, AB.y);
  }
  out[(size_t)MTOK * DH + g] = H;            // h_last
}

// ---- scan pass C: apply prefix, write h_all ----
__global__ __launch_bounds__(256) void scan_apply(const unsigned* __restrict__ ab,
                                                  const float* __restrict__ prefix,
                                                  float* __restrict__ out) {
  int id = blockIdx.x * 256 + threadIdx.x;   // 262144
  int q = id & 4095;
  int c = id >> 12;
  int g = q * 2;
  int b = g >> 11, ch = g & 2047;
  size_t base = (size_t)(b * SEQ + c * CL) * DH + ch;
  const unsigned* p = ab + base;
  float* o = out + base;
  float h0 = prefix[c * NCH + g];
  float h1 = prefix[c * NCH + g + 1];
  #pragma unroll 8
  for (int i = 0; i < CL; i++) {
    uint2 u = *reinterpret_cast<const uint2*>(p + (size_t)i * DH);
    float a0 = bf2f(u.x & 0xffffu), b0 = bf2f(u.x >> 16);
    float a1 = bf2f(u.y & 0xffffu), b1 = bf2f(u.y >> 16);
    h0 = fmaf(a0, h0, b0);
    h1 = fmaf(a1, h1, b1);
    float2 w = {h0, h1};
    *reinterpret_cast<float2*>(o + (size_t)i * DH) = w;
  }
}

extern "C" void kernel_launch(void* const* d_in, const int* in_sizes, int n_in,
                              void* d_out, int out_size, void* d_ws, size_t ws_size,
                              hipStream_t stream) {
  (void)in_sizes; (void)n_in; (void)out_size; (void)ws_size;
  const float* x      = (const float*)d_in[0];
  const float* hidden = (const float*)d_in[1];
  const float* Wd     = (const float*)d_in[2];
  const float* We     = (const float*)d_in[3];
  const float* be     = (const float*)d_in[4];
  const float* Wg     = (const float*)d_in[5];
  const float* bg     = (const float*)d_in[6];
  const float* Wv     = (const float*)d_in[7];
  const float* bv     = (const float*)d_in[8];
  float* out = (float*)d_out;
  char* ws = (char*)d_ws;

  // ws_ab is MTOK*DH uint32 = 134217728 B.
  unsigned*       ws_ab    = (unsigned*)(ws);                    // [0, 134217728)
  unsigned short* Xb       = (unsigned short*)(ws + 134217728);  // 33554432 B
  unsigned short* Pb       = (unsigned short*)(ws + 167772160);  // 8388608 B
  unsigned short* Wvb      = (unsigned short*)(ws + 176160768);  // 4194304 B
  unsigned short* Wgb      = (unsigned short*)(ws + 180355072);  // 4194304 B
  unsigned short* Wdb      = (unsigned short*)(ws + 184549376);  // 524288 B
  unsigned short* Web      = (unsigned short*)(ws + 185073664);  // 1048576 B
  float*          hd_gate  = (float*)(ws + 186122240);           // 32768 B
  float*          hd_delta = (float*)(ws + 186155008);           // 4096 B
  // partial lives in d_out's h_all region: gemm_fused writes it, scan_chunks
  // consumes it, then scan_apply overwrites the region. Stream-ordered.
  float2*         partial  = (float2*)out;                       // 4194304 B
  // prefix aliases Xb (dead after gemm_fused; written/read only by scans).
  float*          prefix   = (float*)(ws + 134217728);           // 2097152 B

  // merged bf16 casts
  cast_all<<<2048, 256, 0, stream>>>(x, Wv, Wg, Wd, We, Xb, Wvb, Wgb, Wdb, Web);
  // hidden-part bias projections
  hd_kernel<<<(DH + DR) / 4, 256, 0, stream>>>(Wg, Wd, hidden, hd_gate, hd_delta);
  // P = silu(delta_latent)
  gemm_P<<<dim3(MTOK / 128, DR / 64), 256, 0, stream>>>(Xb, Wdb, hd_delta, Pb);
  // packed (a,b) + fused chunk partials
  gemm_fused<<<dim3(MTOK / 128, DH / 64), 256, 0, stream>>>(
      Xb, Wvb, Wgb, Pb, Web, bv, bg, be, hd_gate, ws_ab, partial);
  // hierarchical linear-recurrence scan (pass A fused into gemm_fused)
  scan_chunks<<<NCH / 256, 256, 0, stream>>>(partial, hidden, prefix, out);
  scan_apply<<<(NCH/2) * NCHUNK / 256, 256, 0, stream>>>(ws_ab, prefix, out);
}

// Round 13
// 301.734 us; speedup vs baseline: 1.1036x; 1.1036x over previous
//
#include <hip/hip_runtime.h>
#include <hip/hip_bf16.h>
#include <cstdint>

#define DIN 1024
#define DH  2048
#define DR  256
#define SEQ 4096
#define NB  4
#define MTOK (NB*SEQ)   // 16384
#define NCHUNK 64
#define CL (SEQ/NCHUNK) // 64
#define NCH (NB*DH)     // 8192 (b,ch) lanes

typedef __attribute__((ext_vector_type(8))) short bf16x8;
typedef __attribute__((ext_vector_type(4))) float f32x4;

__device__ __forceinline__ unsigned short f2bf(float f) {
  union { float f; unsigned u; } v; v.f = f;
  unsigned r = v.u + 0x7fffu + ((v.u >> 16) & 1u);
  return (unsigned short)(r >> 16);
}

__device__ __forceinline__ float bf2f(unsigned s) {
  union { unsigned u; float f; } v; v.u = s << 16; return v.f;
}

// pack two f32 -> (bf16(a) | bf16(b)<<16) via HW round-to-nearest-even
__device__ __forceinline__ unsigned pack_ab(float a, float b) {
  unsigned r;
  asm("v_cvt_pk_bf16_f32 %0, %1, %2" : "=v"(r) : "v"(a), "v"(b));
  return r;
}

__device__ __forceinline__ unsigned pack2bf(float a, float b) {
  unsigned r;
  asm("v_cvt_pk_bf16_f32 %0, %1, %2" : "=v"(r) : "v"(a), "v"(b));
  return r;
}

__device__ __forceinline__ float fast_rcp(float x) {
  float r;
  asm("v_rcp_f32_e32 %0, %1" : "=v"(r) : "v"(x));
  return r;
}

__device__ __forceinline__ float sigmoidf_(float x) {
  return fast_rcp(1.0f + __expf(-x));
}

// ---- single merged cast kernel: all 5 f32->bf16 casts, region-resolved ----
__global__ void cast_all(const float* __restrict__ x,  const float* __restrict__ Wv,
                         const float* __restrict__ Wg, const float* __restrict__ Wd,
                         const float* __restrict__ We,
                         unsigned short* __restrict__ Xb,  unsigned short* __restrict__ Wvb,
                         unsigned short* __restrict__ Wgb, unsigned short* __restrict__ Wdb,
                         unsigned short* __restrict__ Web) {
  const int total = 5439488;
  for (int i = blockIdx.x * blockDim.x + threadIdx.x; i < total;
       i += gridDim.x * blockDim.x) {
    const float* src; unsigned short* dst;
    int li, r, c4, ld, cols;
    if (i < 4194304)      { li = i;           src = x;  dst = Xb;  r = li >> 8; c4 = li & 255; ld = 1024; cols = 1024; }
    else if (i < 4718592) { li = i - 4194304; src = Wv; dst = Wvb; r = li >> 8; c4 = li & 255; ld = 1024; cols = 1024; }
    else if (i < 5242880) { li = i - 4718592; src = Wg; dst = Wgb; r = li >> 8; c4 = li & 255; ld = 3072; cols = 1024; }
    else if (i < 5308416) { li = i - 5242880; src = Wd; dst = Wdb; r = li >> 8; c4 = li & 255; ld = 3072; cols = 1024; }
    else                  { li = i - 5308416; src = We; dst = Web; r = li >> 6; c4 = li & 63;  ld = 256;  cols = 256; }
    const float4 v = *reinterpret_cast<const float4*>(src + (size_t)r * ld + c4 * 4);
    uint2 o;
    o.x = pack2bf(v.x, v.y);
    o.y = pack2bf(v.z, v.w);
    *reinterpret_cast<uint2*>(dst + (size_t)r * cols + c4 * 4) = o;
  }
}

// ---- hidden-part projections ----
__global__ void hd_kernel(const float* __restrict__ Wg, const float* __restrict__ Wd,
                          const float* __restrict__ hidden,
                          float* __restrict__ hd_gate, float* __restrict__ hd_delta) {
  int wid  = (blockIdx.x * blockDim.x + threadIdx.x) >> 6;
  int lane = threadIdx.x & 63;
  if (wid >= DH + DR) return;
  const float* wrow;
  int ch; bool isGate;
  if (wid < DH) { isGate = true;  ch = wid;      wrow = Wg + (size_t)ch * (DIN + DH) + DIN; }
  else          { isGate = false; ch = wid - DH; wrow = Wd + (size_t)ch * (DIN + DH) + DIN; }
  float acc[NB] = {0.f, 0.f, 0.f, 0.f};
  for (int k = lane; k < DH; k += 64) {
    float w = wrow[k];
    #pragma unroll
    for (int b = 0; b < NB; b++) acc[b] += w * hidden[b * DH + k];
  }
  #pragma unroll
  for (int b = 0; b < NB; b++) {
    float v = acc[b];
    #pragma unroll
    for (int off = 32; off; off >>= 1) v += __shfl_down(v, off);
    if (lane == 0) {
      if (isGate) hd_gate[b * DH + ch] = v;
      else        hd_delta[b * DR + ch] = v;
    }
  }
}

// ---- async LDS staging via global_load_lds (linear LDS dest, pre-swizzled
//      SOURCE, swizzled read). Tile = [rows][64] bf16. ----
__device__ __forceinline__ void stage_async(const unsigned short* __restrict__ src,
                                            int src_ld, unsigned short* lds,
                                            int rows, int wid, int lane) {
  int r8 = lane >> 3;
  int c  = (lane & 7) ^ (r8 & 7);
  const unsigned short* g0 = src + (size_t)r8 * src_ld + c * 8;
  int nsegs = rows >> 3;
  for (int s = wid; s < nsegs; s += 4) {
    const unsigned short* g = g0 + (size_t)(s * 8) * src_ld;
    __builtin_amdgcn_global_load_lds(
        (const __attribute__((address_space(1))) void*)g,
        (__attribute__((address_space(3))) void*)(lds + s * 512),
        16, 0, 0);
  }
}

__device__ __forceinline__ bf16x8 read_frag(const unsigned short* lds, int row,
                                            int kk, int lane) {
  int c = (kk * 4 + (lane >> 4)) ^ (row & 7);
  return *reinterpret_cast<const bf16x8*>(lds + row * 64 + c * 8);
}

// ---- GEMM: P = silu(Xb @ Wd_x^T + hd_delta)  -> bf16 [MTOK][DR]
__global__ __launch_bounds__(256, 2) void gemm_P(
    const unsigned short* __restrict__ Xb, const unsigned short* __restrict__ Wdb,
    const float* __restrict__ hd_delta, unsigned short* __restrict__ P) {
  __shared__ __align__(16) unsigned short As[128 * 64];
  __shared__ __align__(16) unsigned short Bs[64 * 64];
  int tid = threadIdx.x, lane = tid & 63, wid = tid >> 6;
  int wm = wid >> 1, wn = wid & 1;
  int bm0 = blockIdx.x * 128;
  int bn0 = blockIdx.y * 64;
  f32x4 acc[4][2];
  #pragma unroll
  for (int m = 0; m < 4; m++)
    #pragma unroll
    for (int n = 0; n < 2; n++) acc[m][n] = (f32x4){0.f, 0.f, 0.f, 0.f};

  for (int k0 = 0; k0 < DIN; k0 += 64) {
    stage_async(Xb + (size_t)bm0 * DIN + k0, DIN, As, 128, wid, lane);
    stage_async(Wdb + (size_t)bn0 * DIN + k0, DIN, Bs, 64, wid, lane);
    __syncthreads();
    #pragma unroll
    for (int kk = 0; kk < 2; kk++) {
      bf16x8 af[4], bf[2];
      #pragma unroll
      for (int m = 0; m < 4; m++) af[m] = read_frag(As, wm * 64 + m * 16 + (lane & 15), kk, lane);
      #pragma unroll
      for (int n = 0; n < 2; n++) bf[n] = read_frag(Bs, wn * 32 + n * 16 + (lane & 15), kk, lane);
      #pragma unroll
      for (int m = 0; m < 4; m++)
        #pragma unroll
        for (int n = 0; n < 2; n++)
          acc[m][n] = __builtin_amdgcn_mfma_f32_16x16x32_bf16(af[m], bf[n], acc[m][n], 0, 0, 0);
    }
    __syncthreads();
  }
  int batch = bm0 >> 12;
  #pragma unroll
  for (int n = 0; n < 2; n++) {
    int ch = bn0 + wn * 32 + n * 16 + (lane & 15);
    float hd = hd_delta[batch * DR + ch];
    #pragma unroll
    for (int m = 0; m < 4; m++) {
      #pragma unroll
      for (int r = 0; r < 4; r++) {
        int tok = bm0 + wm * 64 + m * 16 + (lane >> 4) * 4 + r;
        float v = acc[m][n][r] + hd;
        v = v * sigmoidf_(v);   // silu
        P[(size_t)tok * DR + ch] = f2bf(v);
      }
    }
  }
}

// ---- fused GEMM producing packed (a,b) bf16 pairs + per-chunk scan partials ----
__global__ __launch_bounds__(256, 2) void gemm_fused(
    const unsigned short* __restrict__ Xb, const unsigned short* __restrict__ Wvb,
    const unsigned short* __restrict__ Wgb, const unsigned short* __restrict__ P,
    const unsigned short* __restrict__ Web,
    const float* __restrict__ b_value, const float* __restrict__ b_gate,
    const float* __restrict__ b_expand, const float* __restrict__ hd_gate,
    unsigned* __restrict__ ws_ab, float2* __restrict__ partial) {
  __shared__ __align__(16) unsigned short As[128 * 64];
  __shared__ __align__(16) unsigned short Bv[64 * 64];
  __shared__ __align__(16) unsigned short Bg[64 * 64];
  int tid = threadIdx.x, lane = tid & 63, wid = tid >> 6;
  int wm = wid >> 1, wn = wid & 1;
  int bm0 = blockIdx.x * 128;
  int bn0 = blockIdx.y * 64;
  f32x4 acc_v[4][2], acc_g[4][2], acc_d[4][2];
  #pragma unroll
  for (int m = 0; m < 4; m++)
    #pragma unroll
    for (int n = 0; n < 2; n++) {
      acc_v[m][n] = (f32x4){0.f, 0.f, 0.f, 0.f};
      acc_g[m][n] = (f32x4){0.f, 0.f, 0.f, 0.f};
      acc_d[m][n] = (f32x4){0.f, 0.f, 0.f, 0.f};
    }

  // K1: value + gate projections (share the X tile)
  for (int k0 = 0; k0 < DIN; k0 += 64) {
    stage_async(Xb + (size_t)bm0 * DIN + k0, DIN, As, 128, wid, lane);
    stage_async(Wvb + (size_t)bn0 * DIN + k0, DIN, Bv, 64, wid, lane);
    stage_async(Wgb + (size_t)bn0 * DIN + k0, DIN, Bg, 64, wid, lane);
    __syncthreads();
    #pragma unroll
    for (int kk = 0; kk < 2; kk++) {
      bf16x8 af[4], bvf[2], bgf[2];
      #pragma unroll
      for (int m = 0; m < 4; m++) af[m] = read_frag(As, wm * 64 + m * 16 + (lane & 15), kk, lane);
      #pragma unroll
      for (int n = 0; n < 2; n++) {
        bvf[n] = read_frag(Bv, wn * 32 + n * 16 + (lane & 15), kk, lane);
        bgf[n] = read_frag(Bg, wn * 32 + n * 16 + (lane & 15), kk, lane);
      }
      #pragma unroll
      for (int m = 0; m < 4; m++)
        #pragma unroll
        for (int n = 0; n < 2; n++) {
          acc_v[m][n] = __builtin_amdgcn_mfma_f32_16x16x32_bf16(af[m], bvf[n], acc_v[m][n], 0, 0, 0);
          acc_g[m][n] = __builtin_amdgcn_mfma_f32_16x16x32_bf16(af[m], bgf[n], acc_g[m][n], 0, 0, 0);
        }
    }
    __syncthreads();
  }
  // K2: delta expand (P @ We^T), K = 256
  for (int k0 = 0; k0 < DR; k0 += 64) {
    stage_async(P + (size_t)bm0 * DR + k0, DR, As, 128, wid, lane);
    stage_async(Web + (size_t)bn0 * DR + k0, DR, Bv, 64, wid, lane);
    __syncthreads();
    #pragma unroll
    for (int kk = 0; kk < 2; kk++) {
      bf16x8 af[4], bef[2];
      #pragma unroll
      for (int m = 0; m < 4; m++) af[m] = read_frag(As, wm * 64 + m * 16 + (lane & 15), kk, lane);
      #pragma unroll
      for (int n = 0; n < 2; n++) bef[n] = read_frag(Bv, wn * 32 + n * 16 + (lane & 15), kk, lane);
      #pragma unroll
      for (int m = 0; m < 4; m++)
        #pragma unroll
        for (int n = 0; n < 2; n++)
          acc_d[m][n] = __builtin_amdgcn_mfma_f32_16x16x32_bf16(af[m], bef[n], acc_d[m][n], 0, 0, 0);
    }
    __syncthreads();
  }
  // epilogue: pack a = 1-gate, b = gate*(silu(v)+delta); non-temporal store of
  // ws_ab (streaming, written-once-read-once) so it doesn't evict Xb from L3.
  // Also compose the wave's 64-token chunk aggregate (A,B) per channel.
  int batch = bm0 >> 12;
  int cbase = ((bm0 & (SEQ - 1)) >> 6) + wm;   // chunk index within batch
  int q = lane >> 4;
  #pragma unroll
  for (int n = 0; n < 2; n++) {
    int ch = bn0 + wn * 32 + n * 16 + (lane & 15);
    float bv_ = b_value[ch];
    float bg_ = b_gate[ch] + hd_gate[batch * DH + ch];
    float be_ = b_expand[ch];
    unsigned pk[4][4];
    #pragma unroll
    for (int m = 0; m < 4; m++) {
      #pragma unroll
      for (int r = 0; r < 4; r++) {
        int tok = bm0 + wm * 64 + m * 16 + q * 4 + r;
        float vv = acc_v[m][n][r] + bv_;
        vv = vv * sigmoidf_(vv);                       // silu(value)
        float gg = sigmoidf_(acc_g[m][n][r] + bg_);    // gate
        float dd = acc_d[m][n][r] + be_;               // delta
        unsigned pw = pack_ab(1.0f - gg, gg * (vv + dd));
        pk[m][r] = pw;
        __builtin_nontemporal_store(pw, &ws_ab[(size_t)tok * DH + ch]);
      }
    }
    // chunk composition: per-lane 4-run, ordered butterfly over q, fold over m
    float A = 1.f, B = 0.f;
    #pragma unroll
    for (int m = 0; m < 4; m++) {
      float Am = 1.f, Bm = 0.f;
      #pragma unroll
      for (int r = 0; r < 4; r++) {
        float ar = bf2f(pk[m][r] & 0xffffu), br = bf2f(pk[m][r] >> 16);
        Bm = fmaf(ar, Bm, br); Am *= ar;
      }
      // ordered butterfly across q (lane bits 4,5): compose lower-q first
      {
        float Ao = __shfl_xor(Am, 16), Bo = __shfl_xor(Bm, 16);
        bool hi = (lane >> 4) & 1;
        float A1 = hi ? Ao : Am, B1 = hi ? Bo : Bm;
        float A2 = hi ? Am : Ao, B2 = hi ? Bm : Bo;
        Am = A2 * A1; Bm = fmaf(A2, B1, B2);
      }
      {
        float Ao = __shfl_xor(Am, 32), Bo = __shfl_xor(Bm, 32);
        bool hi = (lane >> 5) & 1;
        float A1 = hi ? Ao : Am, B1 = hi ? Bo : Bm;
        float A2 = hi ? Am : Ao, B2 = hi ? Bm : Bo;
        Am = A2 * A1; Bm = fmaf(A2, B1, B2);
      }
      B = fmaf(Am, B, Bm); A *= Am;
    }
    if (lane < 16) {
      float2 w = {A, B};
      partial[(size_t)cbase * NCH + batch * DH + ch] = w;
    }
  }
}

// ---- scan pass B: sequential scan over chunk aggregates, emit prefixes + h_last ----
__global__ void scan_chunks(const float2* __restrict__ partial,
                            const float* __restrict__ hidden,
                            float* __restrict__ prefix, float* __restrict__ out) {
  int g = blockIdx.x * 256 + threadIdx.x;    // 8192
  float H = hidden[g];
  for (int c = 0; c < NCHUNK; c++) {
    prefix[c * NCH + g] = H;
    float2 AB = partial[(size_t)c * NCH + g];
    H = fmaf(AB.x, H, AB.y);
  }
  out[(size_t)MTOK * DH + g] = H;            // h_last
}

// ---- scan pass C: apply prefix, write h_all ----
__global__ __launch_bounds__(256) void scan_apply(const unsigned* __restrict__ ab,
                                                  const float* __restrict__ prefix,
                                                  float* __restrict__ out) {
  int id = blockIdx.x * 256 + threadIdx.x;   // 262144
  int q = id & 4095;
  int c = id >> 12;
  int g = q * 2;
  int b = g >> 11, ch = g & 2047;
  size_t base = (size_t)(b * SEQ + c * CL) * DH + ch;
  const unsigned* p = ab + base;
  float* o = out + base;
  float h0 = prefix[c * NCH + g];
  float h1 = prefix[c * NCH + g + 1];
  #pragma unroll 8
  for (int i = 0; i < CL; i++) {
    uint2 u = *reinterpret_cast<const uint2*>(p + (size_t)i * DH);
    float a0 = bf2f(u.x & 0xffffu), b0 = bf2f(u.x >> 16);
    float a1 = bf2f(u.y & 0xffffu), b1 = bf2f(u.y >> 16);
    h0 = fmaf(a0, h0, b0);
    h1 = fmaf(a1, h1, b1);
    float2 w = {h0, h1};
    *reinterpret_cast<float2*>(o + (size_t)i * DH) = w;
  }
}

extern "C" void kernel_launch(void* const* d_in, const int* in_sizes, int n_in,
                              void* d_out, int out_size, void* d_ws, size_t ws_size,
                              hipStream_t stream) {
  (void)in_sizes; (void)n_in; (void)out_size; (void)ws_size;
  const float* x      = (const float*)d_in[0];
  const float* hidden = (const float*)d_in[1];
  const float* Wd     = (const float*)d_in[2];
  const float* We     = (const float*)d_in[3];
  const float* be     = (const float*)d_in[4];
  const float* Wg     = (const float*)d_in[5];
  const float* bg     = (const float*)d_in[6];
  const float* Wv     = (const float*)d_in[7];
  const float* bv     = (const float*)d_in[8];
  float* out = (float*)d_out;
  char* ws = (char*)d_ws;

  // ws_ab is MTOK*DH uint32 = 134217728 B.
  unsigned*       ws_ab    = (unsigned*)(ws);                    // [0, 134217728)
  unsigned short* Xb       = (unsigned short*)(ws + 134217728);  // 33554432 B
  unsigned short* Pb       = (unsigned short*)(ws + 167772160);  // 8388608 B
  unsigned short* Wvb      = (unsigned short*)(ws + 176160768);  // 4194304 B
  unsigned short* Wgb      = (unsigned short*)(ws + 180355072);  // 4194304 B
  unsigned short* Wdb      = (unsigned short*)(ws + 184549376);  // 524288 B
  unsigned short* Web      = (unsigned short*)(ws + 185073664);  // 1048576 B
  float*          hd_gate  = (float*)(ws + 186122240);           // 32768 B
  float*          hd_delta = (float*)(ws + 186155008);           // 4096 B
  // partial lives in d_out's h_all region: gemm_fused writes it, scan_chunks
  // consumes it, then scan_apply overwrites the region. Stream-ordered.
  float2*         partial  = (float2*)out;                       // 4194304 B
  // prefix aliases Xb (dead after gemm_fused; written/read only by scans).
  float*          prefix   = (float*)(ws + 134217728);           // 2097152 B

  // merged bf16 casts
  cast_all<<<2048, 256, 0, stream>>>(x, Wv, Wg, Wd, We, Xb, Wvb, Wgb, Wdb, Web);
  // hidden-part bias projections
  hd_kernel<<<(DH + DR) / 4, 256, 0, stream>>>(Wg, Wd, hidden, hd_gate, hd_delta);
  // P = silu(delta_latent)
  gemm_P<<<dim3(MTOK / 128, DR / 64), 256, 0, stream>>>(Xb, Wdb, hd_delta, Pb);
  // packed (a,b) + fused chunk partials
  gemm_fused<<<dim3(MTOK / 128, DH / 64), 256, 0, stream>>>(
      Xb, Wvb, Wgb, Pb, Web, bv, bg, be, hd_gate, ws_ab, partial);
  // hierarchical linear-recurrence scan (pass A fused into gemm_fused)
  scan_chunks<<<NCH / 256, 256, 0, stream>>>(partial, hidden, prefix, out);
  scan_apply<<<(NCH/2) * NCHUNK / 256, 256, 0, stream>>>(ws_ab, prefix, out);
}

// Round 15
// 295.259 us; speedup vs baseline: 1.1278x; 1.0219x over previous
//
#include <hip/hip_runtime.h>
#include <hip/hip_bf16.h>
#include <cstdint>

#define DIN 1024
#define DH  2048
#define DR  256
#define SEQ 4096
#define NB  4
#define MTOK (NB*SEQ)   // 16384
#define NCHUNK 64
#define CL (SEQ/NCHUNK) // 64
#define NCH (NB*DH)     // 8192 (b,ch) lanes

typedef __attribute__((ext_vector_type(8))) short bf16x8;
typedef __attribute__((ext_vector_type(4))) float f32x4;
typedef __attribute__((ext_vector_type(2))) float f32x2;
typedef __attribute__((ext_vector_type(2))) unsigned u32x2;

__device__ __forceinline__ unsigned short f2bf(float f) {
  union { float f; unsigned u; } v; v.f = f;
  unsigned r = v.u + 0x7fffu + ((v.u >> 16) & 1u);
  return (unsigned short)(r >> 16);
}

__device__ __forceinline__ float bf2f(unsigned s) {
  union { unsigned u; float f; } v; v.u = s << 16; return v.f;
}

// pack two f32 -> (bf16(a) | bf16(b)<<16) via HW round-to-nearest-even
__device__ __forceinline__ unsigned pack_ab(float a, float b) {
  unsigned r;
  asm("v_cvt_pk_bf16_f32 %0, %1, %2" : "=v"(r) : "v"(a), "v"(b));
  return r;
}

__device__ __forceinline__ unsigned pack2bf(float a, float b) {
  unsigned r;
  asm("v_cvt_pk_bf16_f32 %0, %1, %2" : "=v"(r) : "v"(a), "v"(b));
  return r;
}

__device__ __forceinline__ float fast_rcp(float x) {
  float r;
  asm("v_rcp_f32_e32 %0, %1" : "=v"(r) : "v"(x));
  return r;
}

__device__ __forceinline__ float sigmoidf_(float x) {
  return fast_rcp(1.0f + __expf(-x));
}

// ---- single merged cast kernel: all 5 f32->bf16 casts, region-resolved ----
__global__ void cast_all(const float* __restrict__ x,  const float* __restrict__ Wv,
                         const float* __restrict__ Wg, const float* __restrict__ Wd,
                         const float* __restrict__ We,
                         unsigned short* __restrict__ Xb,  unsigned short* __restrict__ Wvb,
                         unsigned short* __restrict__ Wgb, unsigned short* __restrict__ Wdb,
                         unsigned short* __restrict__ Web) {
  const int total = 5439488;
  for (int i = blockIdx.x * blockDim.x + threadIdx.x; i < total;
       i += gridDim.x * blockDim.x) {
    const float* src; unsigned short* dst;
    int li, r, c4, ld, cols;
    if (i < 4194304)      { li = i;           src = x;  dst = Xb;  r = li >> 8; c4 = li & 255; ld = 1024; cols = 1024; }
    else if (i < 4718592) { li = i - 4194304; src = Wv; dst = Wvb; r = li >> 8; c4 = li & 255; ld = 1024; cols = 1024; }
    else if (i < 5242880) { li = i - 4718592; src = Wg; dst = Wgb; r = li >> 8; c4 = li & 255; ld = 3072; cols = 1024; }
    else if (i < 5308416) { li = i - 5242880; src = Wd; dst = Wdb; r = li >> 8; c4 = li & 255; ld = 3072; cols = 1024; }
    else                  { li = i - 5308416; src = We; dst = Web; r = li >> 6; c4 = li & 63;  ld = 256;  cols = 256; }
    const float4 v = *reinterpret_cast<const float4*>(src + (size_t)r * ld + c4 * 4);
    uint2 o;
    o.x = pack2bf(v.x, v.y);
    o.y = pack2bf(v.z, v.w);
    *reinterpret_cast<uint2*>(dst + (size_t)r * cols + c4 * 4) = o;
  }
}

// ---- hidden-part projections ----
__global__ void hd_kernel(const float* __restrict__ Wg, const float* __restrict__ Wd,
                          const float* __restrict__ hidden,
                          float* __restrict__ hd_gate, float* __restrict__ hd_delta) {
  int wid  = (blockIdx.x * blockDim.x + threadIdx.x) >> 6;
  int lane = threadIdx.x & 63;
  if (wid >= DH + DR) return;
  const float* wrow;
  int ch; bool isGate;
  if (wid < DH) { isGate = true;  ch = wid;      wrow = Wg + (size_t)ch * (DIN + DH) + DIN; }
  else          { isGate = false; ch = wid - DH; wrow = Wd + (size_t)ch * (DIN + DH) + DIN; }
  float acc[NB] = {0.f, 0.f, 0.f, 0.f};
  for (int k = lane; k < DH; k += 64) {
    float w = wrow[k];
    #pragma unroll
    for (int b = 0; b < NB; b++) acc[b] += w * hidden[b * DH + k];
  }
  #pragma unroll
  for (int b = 0; b < NB; b++) {
    float v = acc[b];
    #pragma unroll
    for (int off = 32; off; off >>= 1) v += __shfl_down(v, off);
    if (lane == 0) {
      if (isGate) hd_gate[b * DH + ch] = v;
      else        hd_delta[b * DR + ch] = v;
    }
  }
}

// ---- async LDS staging via global_load_lds (linear LDS dest, pre-swizzled
//      SOURCE, swizzled read). Tile = [rows][64] bf16. ----
__device__ __forceinline__ void stage_async(const unsigned short* __restrict__ src,
                                            int src_ld, unsigned short* lds,
                                            int rows, int wid, int lane) {
  int r8 = lane >> 3;
  int c  = (lane & 7) ^ (r8 & 7);
  const unsigned short* g0 = src + (size_t)r8 * src_ld + c * 8;
  int nsegs = rows >> 3;
  for (int s = wid; s < nsegs; s += 4) {
    const unsigned short* g = g0 + (size_t)(s * 8) * src_ld;
    __builtin_amdgcn_global_load_lds(
        (const __attribute__((address_space(1))) void*)g,
        (__attribute__((address_space(3))) void*)(lds + s * 512),
        16, 0, 0);
  }
}

__device__ __forceinline__ bf16x8 read_frag(const unsigned short* lds, int row,
                                            int kk, int lane) {
  int c = (kk * 4 + (lane >> 4)) ^ (row & 7);
  return *reinterpret_cast<const bf16x8*>(lds + row * 64 + c * 8);
}

// ---- GEMM: P = silu(Xb @ Wd_x^T + hd_delta)  -> bf16 [MTOK][DR]
// grid = dim3(N-panels, M-tiles): x = N so the dispatch sweep keeps each
// M-tile's X slab L2-hot across all N-panels.
__global__ __launch_bounds__(256, 2) void gemm_P(
    const unsigned short* __restrict__ Xb, const unsigned short* __restrict__ Wdb,
    const float* __restrict__ hd_delta, unsigned short* __restrict__ P) {
  __shared__ __align__(16) unsigned short As[128 * 64];
  __shared__ __align__(16) unsigned short Bs[64 * 64];
  int tid = threadIdx.x, lane = tid & 63, wid = tid >> 6;
  int wm = wid >> 1, wn = wid & 1;
  int bm0 = blockIdx.y * 128;
  int bn0 = blockIdx.x * 64;
  f32x4 acc[4][2];
  #pragma unroll
  for (int m = 0; m < 4; m++)
    #pragma unroll
    for (int n = 0; n < 2; n++) acc[m][n] = (f32x4){0.f, 0.f, 0.f, 0.f};

  for (int k0 = 0; k0 < DIN; k0 += 64) {
    stage_async(Xb + (size_t)bm0 * DIN + k0, DIN, As, 128, wid, lane);
    stage_async(Wdb + (size_t)bn0 * DIN + k0, DIN, Bs, 64, wid, lane);
    __syncthreads();
    #pragma unroll
    for (int kk = 0; kk < 2; kk++) {
      bf16x8 af[4], bf[2];
      #pragma unroll
      for (int m = 0; m < 4; m++) af[m] = read_frag(As, wm * 64 + m * 16 + (lane & 15), kk, lane);
      #pragma unroll
      for (int n = 0; n < 2; n++) bf[n] = read_frag(Bs, wn * 32 + n * 16 + (lane & 15), kk, lane);
      #pragma unroll
      for (int m = 0; m < 4; m++)
        #pragma unroll
        for (int n = 0; n < 2; n++)
          acc[m][n] = __builtin_amdgcn_mfma_f32_16x16x32_bf16(af[m], bf[n], acc[m][n], 0, 0, 0);
    }
    __syncthreads();
  }
  int batch = bm0 >> 12;
  #pragma unroll
  for (int n = 0; n < 2; n++) {
    int ch = bn0 + wn * 32 + n * 16 + (lane & 15);
    float hd = hd_delta[batch * DR + ch];
    #pragma unroll
    for (int m = 0; m < 4; m++) {
      #pragma unroll
      for (int r = 0; r < 4; r++) {
        int tok = bm0 + wm * 64 + m * 16 + (lane >> 4) * 4 + r;
        float v = acc[m][n][r] + hd;
        v = v * sigmoidf_(v);   // silu
        P[(size_t)tok * DR + ch] = f2bf(v);
      }
    }
  }
}

// ---- fused GEMM producing packed (a,b) bf16 pairs + per-chunk scan partials ----
// grid = dim3(32 N-panels, 128 M-tiles) — see gemm_P note.
__global__ __launch_bounds__(256, 2) void gemm_fused(
    const unsigned short* __restrict__ Xb, const unsigned short* __restrict__ Wvb,
    const unsigned short* __restrict__ Wgb, const unsigned short* __restrict__ P,
    const unsigned short* __restrict__ Web,
    const float* __restrict__ b_value, const float* __restrict__ b_gate,
    const float* __restrict__ b_expand, const float* __restrict__ hd_gate,
    unsigned* __restrict__ ws_ab, float2* __restrict__ partial) {
  __shared__ __align__(16) unsigned short As[128 * 64];
  __shared__ __align__(16) unsigned short Bv[64 * 64];
  __shared__ __align__(16) unsigned short Bg[64 * 64];
  int tid = threadIdx.x, lane = tid & 63, wid = tid >> 6;
  int wm = wid >> 1, wn = wid & 1;
  int bm0 = blockIdx.y * 128;
  int bn0 = blockIdx.x * 64;
  f32x4 acc_v[4][2], acc_g[4][2], acc_d[4][2];
  #pragma unroll
  for (int m = 0; m < 4; m++)
    #pragma unroll
    for (int n = 0; n < 2; n++) {
      acc_v[m][n] = (f32x4){0.f, 0.f, 0.f, 0.f};
      acc_g[m][n] = (f32x4){0.f, 0.f, 0.f, 0.f};
      acc_d[m][n] = (f32x4){0.f, 0.f, 0.f, 0.f};
    }

  // K1: value + gate projections (share the X tile)
  for (int k0 = 0; k0 < DIN; k0 += 64) {
    stage_async(Xb + (size_t)bm0 * DIN + k0, DIN, As, 128, wid, lane);
    stage_async(Wvb + (size_t)bn0 * DIN + k0, DIN, Bv, 64, wid, lane);
    stage_async(Wgb + (size_t)bn0 * DIN + k0, DIN, Bg, 64, wid, lane);
    __syncthreads();
    #pragma unroll
    for (int kk = 0; kk < 2; kk++) {
      bf16x8 af[4], bvf[2], bgf[2];
      #pragma unroll
      for (int m = 0; m < 4; m++) af[m] = read_frag(As, wm * 64 + m * 16 + (lane & 15), kk, lane);
      #pragma unroll
      for (int n = 0; n < 2; n++) {
        bvf[n] = read_frag(Bv, wn * 32 + n * 16 + (lane & 15), kk, lane);
        bgf[n] = read_frag(Bg, wn * 32 + n * 16 + (lane & 15), kk, lane);
      }
      #pragma unroll
      for (int m = 0; m < 4; m++)
        #pragma unroll
        for (int n = 0; n < 2; n++) {
          acc_v[m][n] = __builtin_amdgcn_mfma_f32_16x16x32_bf16(af[m], bvf[n], acc_v[m][n], 0, 0, 0);
          acc_g[m][n] = __builtin_amdgcn_mfma_f32_16x16x32_bf16(af[m], bgf[n], acc_g[m][n], 0, 0, 0);
        }
    }
    __syncthreads();
  }
  // K2: delta expand (P @ We^T), K = 256
  for (int k0 = 0; k0 < DR; k0 += 64) {
    stage_async(P + (size_t)bm0 * DR + k0, DR, As, 128, wid, lane);
    stage_async(Web + (size_t)bn0 * DR + k0, DR, Bv, 64, wid, lane);
    __syncthreads();
    #pragma unroll
    for (int kk = 0; kk < 2; kk++) {
      bf16x8 af[4], bef[2];
      #pragma unroll
      for (int m = 0; m < 4; m++) af[m] = read_frag(As, wm * 64 + m * 16 + (lane & 15), kk, lane);
      #pragma unroll
      for (int n = 0; n < 2; n++) bef[n] = read_frag(Bv, wn * 32 + n * 16 + (lane & 15), kk, lane);
      #pragma unroll
      for (int m = 0; m < 4; m++)
        #pragma unroll
        for (int n = 0; n < 2; n++)
          acc_d[m][n] = __builtin_amdgcn_mfma_f32_16x16x32_bf16(af[m], bef[n], acc_d[m][n], 0, 0, 0);
    }
    __syncthreads();
  }
  // epilogue: pack a = 1-gate, b = gate*(silu(v)+delta); non-temporal ws_ab
  // stores; compose the wave's 64-token chunk aggregate (A,B) per channel.
  int batch = bm0 >> 12;
  int cbase = ((bm0 & (SEQ - 1)) >> 6) + wm;   // chunk index within batch
  int q = lane >> 4;
  #pragma unroll
  for (int n = 0; n < 2; n++) {
    int ch = bn0 + wn * 32 + n * 16 + (lane & 15);
    float bv_ = b_value[ch];
    float bg_ = b_gate[ch] + hd_gate[batch * DH + ch];
    float be_ = b_expand[ch];
    unsigned pk[4][4];
    #pragma unroll
    for (int m = 0; m < 4; m++) {
      #pragma unroll
      for (int r = 0; r < 4; r++) {
        int tok = bm0 + wm * 64 + m * 16 + q * 4 + r;
        float vv = acc_v[m][n][r] + bv_;
        vv = vv * sigmoidf_(vv);                       // silu(value)
        float gg = sigmoidf_(acc_g[m][n][r] + bg_);    // gate
        float dd = acc_d[m][n][r] + be_;               // delta
        unsigned pw = pack_ab(1.0f - gg, gg * (vv + dd));
        pk[m][r] = pw;
        __builtin_nontemporal_store(pw, &ws_ab[(size_t)tok * DH + ch]);
      }
    }
    // chunk composition: per-lane 4-run, ordered butterfly over q, fold over m
    float A = 1.f, B = 0.f;
    #pragma unroll
    for (int m = 0; m < 4; m++) {
      float Am = 1.f, Bm = 0.f;
      #pragma unroll
      for (int r = 0; r < 4; r++) {
        float ar = bf2f(pk[m][r] & 0xffffu), br = bf2f(pk[m][r] >> 16);
        Bm = fmaf(ar, Bm, br); Am *= ar;
      }
      // ordered butterfly across q (lane bits 4,5): compose lower-q first
      {
        float Ao = __shfl_xor(Am, 16), Bo = __shfl_xor(Bm, 16);
        bool hi = (lane >> 4) & 1;
        float A1 = hi ? Ao : Am, B1 = hi ? Bo : Bm;
        float A2 = hi ? Am : Ao, B2 = hi ? Bm : Bo;
        Am = A2 * A1; Bm = fmaf(A2, B1, B2);
      }
      {
        float Ao = __shfl_xor(Am, 32), Bo = __shfl_xor(Bm, 32);
        bool hi = (lane >> 5) & 1;
        float A1 = hi ? Ao : Am, B1 = hi ? Bo : Bm;
        float A2 = hi ? Am : Ao, B2 = hi ? Bm : Bo;
        Am = A2 * A1; Bm = fmaf(A2, B1, B2);
      }
      B = fmaf(Am, B, Bm); A *= Am;
    }
    if (lane < 16) {
      float2 w = {A, B};
      partial[(size_t)cbase * NCH + batch * DH + ch] = w;
    }
  }
}

// ---- scan pass B: sequential scan over chunk aggregates, emit prefixes + h_last ----
__global__ void scan_chunks(const float2* __restrict__ partial,
                            const float* __restrict__ hidden,
                            float* __restrict__ prefix, float* __restrict__ out) {
  int g = blockIdx.x * 256 + threadIdx.x;    // 8192
  float H = hidden[g];
  for (int c = 0; c < NCHUNK; c++) {
    prefix[c * NCH + g] = H;
    float2 AB = partial[(size_t)c * NCH + g];
    H = fmaf(AB.x, H, AB.y);
  }
  out[(size_t)MTOK * DH + g] = H;            // h_last
}

// ---- scan pass C: apply prefix, write h_all (streaming: nt loads/stores) ----
__global__ __launch_bounds__(256) void scan_apply(const unsigned* __restrict__ ab,
                                                  const float* __restrict__ prefix,
                                                  float* __restrict__ out) {
  int id = blockIdx.x * 256 + threadIdx.x;   // 262144
  int q = id & 4095;
  int c = id >> 12;
  int g = q * 2;
  int b = g >> 11, ch = g & 2047;
  size_t base = (size_t)(b * SEQ + c * CL) * DH + ch;
  const unsigned* p = ab + base;
  float* o = out + base;
  float h0 = prefix[c * NCH + g];
  float h1 = prefix[c * NCH + g + 1];
  #pragma unroll 8
  for (int i = 0; i < CL; i++) {
    u32x2 u = __builtin_nontemporal_load(
        reinterpret_cast<const u32x2*>(p + (size_t)i * DH));
    float a0 = bf2f(u.x & 0xffffu), b0 = bf2f(u.x >> 16);
    float a1 = bf2f(u.y & 0xffffu), b1 = bf2f(u.y >> 16);
    h0 = fmaf(a0, h0, b0);
    h1 = fmaf(a1, h1, b1);
    f32x2 w = {h0, h1};
    __builtin_nontemporal_store(w, reinterpret_cast<f32x2*>(o + (size_t)i * DH));
  }
}

extern "C" void kernel_launch(void* const* d_in, const int* in_sizes, int n_in,
                              void* d_out, int out_size, void* d_ws, size_t ws_size,
                              hipStream_t stream) {
  (void)in_sizes; (void)n_in; (void)out_size; (void)ws_size;
  const float* x      = (const float*)d_in[0];
  const float* hidden = (const float*)d_in[1];
  const float* Wd     = (const float*)d_in[2];
  const float* We     = (const float*)d_in[3];
  const float* be     = (const float*)d_in[4];
  const float* Wg     = (const float*)d_in[5];
  const float* bg     = (const float*)d_in[6];
  const float* Wv     = (const float*)d_in[7];
  const float* bv     = (const float*)d_in[8];
  float* out = (float*)d_out;
  char* ws = (char*)d_ws;

  // ws_ab is MTOK*DH uint32 = 134217728 B.
  unsigned*       ws_ab    = (unsigned*)(ws);                    // [0, 134217728)
  unsigned short* Xb       = (unsigned short*)(ws + 134217728);  // 33554432 B
  unsigned short* Pb       = (unsigned short*)(ws + 167772160);  // 8388608 B
  unsigned short* Wvb      = (unsigned short*)(ws + 176160768);  // 4194304 B
  unsigned short* Wgb      = (unsigned short*)(ws + 180355072);  // 4194304 B
  unsigned short* Wdb      = (unsigned short*)(ws + 184549376);  // 524288 B
  unsigned short* Web      = (unsigned short*)(ws + 185073664);  // 1048576 B
  float*          hd_gate  = (float*)(ws + 186122240);           // 32768 B
  float*          hd_delta = (float*)(ws + 186155008);           // 4096 B
  // partial lives in d_out's h_all region: gemm_fused writes it, scan_chunks
  // consumes it, then scan_apply overwrites the region. Stream-ordered.
  float2*         partial  = (float2*)out;                       // 4194304 B
  // prefix aliases Xb (dead after gemm_fused; written/read only by scans).
  float*          prefix   = (float*)(ws + 134217728);           // 2097152 B

  // merged bf16 casts
  cast_all<<<2048, 256, 0, stream>>>(x, Wv, Wg, Wd, We, Xb, Wvb, Wgb, Wdb, Web);
  // hidden-part bias projections
  hd_kernel<<<(DH + DR) / 4, 256, 0, stream>>>(Wg, Wd, hidden, hd_gate, hd_delta);
  // P = silu(delta_latent)   (grid: x = N-panels, y = M-tiles)
  gemm_P<<<dim3(DR / 64, MTOK / 128), 256, 0, stream>>>(Xb, Wdb, hd_delta, Pb);
  // packed (a,b) + fused chunk partials   (grid: x = N-panels, y = M-tiles)
  gemm_fused<<<dim3(DH / 64, MTOK / 128), 256, 0, stream>>>(
      Xb, Wvb, Wgb, Pb, Web, bv, bg, be, hd_gate, ws_ab, partial);
  // hierarchical linear-recurrence scan (pass A fused into gemm_fused)
  scan_chunks<<<NCH / 256, 256, 0, stream>>>(partial, hidden, prefix, out);
  scan_apply<<<(NCH/2) * NCHUNK / 256, 256, 0, stream>>>(ws_ab, prefix, out);
}